// Round 1
// baseline (2498.655 us; speedup 1.0000x reference)
//
#include <hip/hip_runtime.h>
#include <math.h>

#define B_ 4
#define T_ 1024
#define D_ 2048
#define NH 16
#define NKV 4
#define HD 128
#define KV_D 512   // NKV * HD

// ---------------------------------------------------------------------------
// fp32 tiled GEMM: C[M,N] = A[M,K] @ Bm[K,N], row-major. 64x64 block, 256 thr,
// 4x4 microtile per thread. Correctness-first baseline (MFMA comes later).
// ---------------------------------------------------------------------------
__global__ __launch_bounds__(256) void gemm_f32(const float* __restrict__ A,
                                                const float* __restrict__ Bm,
                                                float* __restrict__ C,
                                                int M, int N, int K) {
    __shared__ float As[64][17];   // [row][k], pad 17 breaks bank aliasing
    __shared__ float Bs[16][65];   // [k][col]
    const int n0 = blockIdx.x * 64;
    const int m0 = blockIdx.y * 64;
    const int tid = threadIdx.x;
    const int tx = tid & 15;   // col group (4 cols)
    const int ty = tid >> 4;   // row group (4 rows)
    float acc[4][4];
#pragma unroll
    for (int i = 0; i < 4; ++i)
#pragma unroll
        for (int j = 0; j < 4; ++j) acc[i][j] = 0.f;

    for (int k0 = 0; k0 < K; k0 += 16) {
        // A tile 64x16
        {
            const int r = tid >> 4, c = tid & 15;
#pragma unroll
            for (int it = 0; it < 4; ++it)
                As[r + it * 16][c] = A[(size_t)(m0 + r + it * 16) * K + k0 + c];
        }
        // B tile 16x64
        {
            const int r = tid >> 6, c = tid & 63;
#pragma unroll
            for (int it = 0; it < 4; ++it)
                Bs[r + it * 4][c] = Bm[(size_t)(k0 + r + it * 4) * N + n0 + c];
        }
        __syncthreads();
#pragma unroll
        for (int kk = 0; kk < 16; ++kk) {
            float a[4], b[4];
#pragma unroll
            for (int i = 0; i < 4; ++i) a[i] = As[ty * 4 + i][kk];
#pragma unroll
            for (int j = 0; j < 4; ++j) b[j] = Bs[kk][tx * 4 + j];
#pragma unroll
            for (int i = 0; i < 4; ++i)
#pragma unroll
                for (int j = 0; j < 4; ++j) acc[i][j] += a[i] * b[j];
        }
        __syncthreads();
    }
#pragma unroll
    for (int i = 0; i < 4; ++i)
#pragma unroll
        for (int j = 0; j < 4; ++j)
            C[(size_t)(m0 + ty * 4 + i) * N + n0 + tx * 4 + j] = acc[i][j];
}

// ---------------------------------------------------------------------------
// RoPE in-place on Q [B,T,NH*HD] and K [B,T,NKV*HD].
// One thread per (b,t,head,i<64) pair.
// ---------------------------------------------------------------------------
__global__ __launch_bounds__(256) void rope_kernel(float* __restrict__ Qb,
                                                   float* __restrict__ Kb) {
    const int idx = blockIdx.x * blockDim.x + threadIdx.x;
    const int i = idx & 63;
    const int head = (idx >> 6) % (NH + NKV);
    const int bt = idx / (64 * (NH + NKV));
    const int t = bt & (T_ - 1);
    const float inv = powf(10000.0f, -2.0f * (float)i / (float)HD);
    const float ang = (float)t * inv;
    const float c = cosf(ang);
    const float s = sinf(ang);
    float* p;
    if (head < NH) p = Qb + (size_t)bt * D_ + head * HD;
    else           p = Kb + (size_t)bt * KV_D + (head - NH) * HD;
    const float x1 = p[i];
    const float x2 = p[i + 64];
    p[i]      = x1 * c - x2 * s;
    p[i + 64] = x2 * c + x1 * s;
}

// ---------------------------------------------------------------------------
// Flash-style causal attention, fp32, GQA. 32x32 tiles, 128 threads (2 waves).
// thread (row = tid>>2, quad = tid&3): owns score cols {quad+4i} and output
// dims [quad*32, quad*32+32). Online softmax; P broadcast within a quad via
// width-4 shuffles (no P tile in LDS). LDS = 3 * 32*132*4 = 50.7 KB.
// ---------------------------------------------------------------------------
#define QT 32
#define KT 32
#define LPAD 132   // row stride: 16B-aligned, bank = (4c+d)%32 -> <=2-way

__global__ __launch_bounds__(128) void attn_kernel(const float* __restrict__ Qb,
                                                   const float* __restrict__ Kb,
                                                   const float* __restrict__ Vb,
                                                   float* __restrict__ Yb) {
    __shared__ float Qs[QT][LPAD];
    __shared__ float Ks[KT][LPAD];
    __shared__ float Vs[KT][LPAD];

    const int bh = blockIdx.x;            // b*NH + h
    const int qt = blockIdx.y;
    const int b = bh >> 4, h = bh & 15;
    const int kvh = h >> 2;               // GQA: q-head h -> kv-head h/4
    const int q0 = qt * QT;
    const int tid = threadIdx.x;
    const int row = tid >> 2;             // 0..31
    const int quad = tid & 3;

    // Q tile -> LDS (float4, coalesced)
    for (int idx = tid; idx < QT * (HD / 4); idx += 128) {
        const int r = idx >> 5, c4 = idx & 31;
        const float4 v = *(const float4*)&Qb[((size_t)(b * T_ + q0 + r)) * D_ + h * HD + c4 * 4];
        *(float4*)&Qs[r][c4 * 4] = v;
    }

    float m = -INFINITY, l = 0.f;
    float4 acc4[8];
#pragma unroll
    for (int j = 0; j < 8; ++j) acc4[j] = make_float4(0.f, 0.f, 0.f, 0.f);
    const float scale = 0.08838834764831845f;  // 1/sqrt(128)

    for (int kt = 0; kt <= qt; ++kt) {
        const int s0 = kt * KT;
        __syncthreads();  // protect Ks/Vs (and Qs on iter 0) from overwrite
        for (int idx = tid; idx < KT * (HD / 4); idx += 128) {
            const int r = idx >> 5, c4 = idx & 31;
            const size_t base = ((size_t)(b * T_ + s0 + r)) * KV_D + kvh * HD + c4 * 4;
            *(float4*)&Ks[r][c4 * 4] = *(const float4*)&Kb[base];
            *(float4*)&Vs[r][c4 * 4] = *(const float4*)&Vb[base];
        }
        __syncthreads();

        // scores for cols c = quad + 4i
        float p[8];
        float sdot[8];
#pragma unroll
        for (int i = 0; i < 8; ++i) sdot[i] = 0.f;
#pragma unroll 2
        for (int d = 0; d < HD; d += 4) {
            const float4 qd = *(const float4*)&Qs[row][d];
#pragma unroll
            for (int i = 0; i < 8; ++i) {
                const float4 kd = *(const float4*)&Ks[quad + 4 * i][d];
                sdot[i] += qd.x * kd.x + qd.y * kd.y + qd.z * kd.z + qd.w * kd.w;
            }
        }
        float tmax = -INFINITY;
#pragma unroll
        for (int i = 0; i < 8; ++i) {
            const int c = quad + 4 * i;
            float sc = sdot[i] * scale;
            if (s0 + c > q0 + row) sc = -INFINITY;  // causal
            p[i] = sc;
            tmax = fmaxf(tmax, sc);
        }
        tmax = fmaxf(tmax, __shfl_xor(tmax, 1));
        tmax = fmaxf(tmax, __shfl_xor(tmax, 2));
        const float mnew = fmaxf(m, tmax);
        const float alpha = __expf(m - mnew);  // m=-inf -> 0
        float sum = 0.f;
#pragma unroll
        for (int i = 0; i < 8; ++i) {
            p[i] = __expf(p[i] - mnew);  // masked -> exp(-inf)=0
            sum += p[i];
        }
        sum += __shfl_xor(sum, 1);
        sum += __shfl_xor(sum, 2);
        l = l * alpha + sum;
        m = mnew;
#pragma unroll
        for (int j = 0; j < 8; ++j) {
            acc4[j].x *= alpha; acc4[j].y *= alpha; acc4[j].z *= alpha; acc4[j].w *= alpha;
        }
        // PV: p broadcast across the quad via width-4 shuffle
#pragma unroll
        for (int s = 0; s < KT; ++s) {
            const float pv = __shfl(p[s >> 2], s & 3, 4);
            const float4* vrow = (const float4*)&Vs[s][quad * 32];
#pragma unroll
            for (int j = 0; j < 8; ++j) {
                const float4 vv = vrow[j];
                acc4[j].x += pv * vv.x; acc4[j].y += pv * vv.y;
                acc4[j].z += pv * vv.z; acc4[j].w += pv * vv.w;
            }
        }
    }

    const float invl = 1.f / l;
    float* yrow = &Yb[((size_t)(b * T_ + q0 + row)) * D_ + h * HD + quad * 32];
#pragma unroll
    for (int j = 0; j < 8; ++j) {
        float4 o = acc4[j];
        o.x *= invl; o.y *= invl; o.z *= invl; o.w *= invl;
        *(float4*)&yrow[j * 4] = o;
    }
}

// ---------------------------------------------------------------------------
extern "C" void kernel_launch(void* const* d_in, const int* in_sizes, int n_in,
                              void* d_out, int out_size, void* d_ws, size_t ws_size,
                              hipStream_t stream) {
    const float* x  = (const float*)d_in[0];
    const float* Wq = (const float*)d_in[1];
    const float* Wk = (const float*)d_in[2];
    const float* Wv = (const float*)d_in[3];
    const float* Wo = (const float*)d_in[4];
    float* out = (float*)d_out;

    // workspace layout (floats): Q | K | V | Y  = 83.9 MB total
    float* Qb = (float*)d_ws;
    float* Kb = Qb + (size_t)B_ * T_ * D_;
    float* Vb = Kb + (size_t)B_ * T_ * KV_D;
    float* Yb = Vb + (size_t)B_ * T_ * KV_D;

    const int M = B_ * T_;  // 4096
    dim3 blk(256);

    gemm_f32<<<dim3(D_ / 64, M / 64), blk, 0, stream>>>(x, Wq, Qb, M, D_, D_);
    gemm_f32<<<dim3(KV_D / 64, M / 64), blk, 0, stream>>>(x, Wk, Kb, M, KV_D, D_);
    gemm_f32<<<dim3(KV_D / 64, M / 64), blk, 0, stream>>>(x, Wv, Vb, M, KV_D, D_);

    const int rope_total = B_ * T_ * (NH + NKV) * 64;
    rope_kernel<<<rope_total / 256, blk, 0, stream>>>(Qb, Kb);

    attn_kernel<<<dim3(B_ * NH, T_ / QT), dim3(128), 0, stream>>>(Qb, Kb, Vb, Yb);

    gemm_f32<<<dim3(D_ / 64, M / 64), blk, 0, stream>>>(Yb, Wo, out, M, D_, D_);
}

// Round 2
// 1187.902 us; speedup vs baseline: 2.1034x; 2.1034x over previous
//
#include <hip/hip_runtime.h>
#include <math.h>

#define B_ 4
#define T_ 1024
#define D_ 2048
#define NH 16
#define NKV 4
#define HD 128
#define KV_D 512   // NKV * HD

typedef __attribute__((ext_vector_type(8))) short short8;   // 8 x bf16 (4 VGPRs)
typedef __attribute__((ext_vector_type(4))) float f32x4;    // MFMA accumulator

// fp32 -> bf16 round-to-nearest-even (finite inputs)
__device__ __forceinline__ ushort f2b(float f) {
    unsigned u = __float_as_uint(f);
    return (ushort)((u + 0x7fffu + ((u >> 16) & 1u)) >> 16);
}

#define ASYNC_COPY16(g, l)                                                  \
    __builtin_amdgcn_global_load_lds(                                       \
        (const __attribute__((address_space(1))) void*)(g),                 \
        (__attribute__((address_space(3))) void*)(l), 16, 0, 0)

// ---------------------------------------------------------------------------
// cast x (fp32) -> bf16, 4 elements/thread
// ---------------------------------------------------------------------------
__global__ __launch_bounds__(256) void cast_f32_bf16(const float* __restrict__ in,
                                                     ushort* __restrict__ out, int n4) {
    const int i = blockIdx.x * blockDim.x + threadIdx.x;
    if (i >= n4) return;
    const float4 v = ((const float4*)in)[i];
    ushort4 u;
    u.x = f2b(v.x); u.y = f2b(v.y); u.z = f2b(v.z); u.w = f2b(v.w);
    ((ushort4*)out)[i] = u;
}

// ---------------------------------------------------------------------------
// W [K][N] fp32 -> WT [N][K] bf16 (so GEMM B-fragments are k-contiguous)
// ---------------------------------------------------------------------------
__global__ __launch_bounds__(256) void transpose_cast(const float* __restrict__ W,
                                                      ushort* __restrict__ WT,
                                                      int K, int N) {
    __shared__ float tile[32][33];
    const int n0 = blockIdx.x * 32, k0 = blockIdx.y * 32;
    const int tx = threadIdx.x & 31, ty = threadIdx.x >> 5;  // 32 x 8
    for (int i = ty; i < 32; i += 8)
        tile[i][tx] = W[(size_t)(k0 + i) * N + n0 + tx];
    __syncthreads();
    for (int i = ty; i < 32; i += 8)
        WT[(size_t)(n0 + i) * K + k0 + tx] = f2b(tile[tx][i]);
}

// ---------------------------------------------------------------------------
// m97-style bf16 MFMA GEMM: C[M,N] fp32 = A[M,K] bf16 (row-major)
//                                       x BT[N,K] bf16 (row-major, = B^T).
// 128x128 tile, BK=32, 256 thr = 4 waves (2x2 of 64x64), 4x4 MFMA 16x16x32
// per wave. Staging via global_load_lds width-16 (wave-uniform base + lane*16:
// LDS is unpadded row-major [128][32] bf16, thread t -> byte offset t*16).
// ---------------------------------------------------------------------------
__global__ __launch_bounds__(256) void gemm_bf16(const ushort* __restrict__ A,
                                                 const ushort* __restrict__ BT,
                                                 float* __restrict__ C,
                                                 int M, int N, int K) {
    __shared__ ushort As[128 * 32];
    __shared__ ushort Bs[128 * 32];
    const int tid = threadIdx.x;
    const int m0 = blockIdx.y * 128, n0 = blockIdx.x * 128;
    const int wave = tid >> 6, lane = tid & 63;
    const int wm = (wave >> 1) * 64, wn = (wave & 1) * 64;
    const int lrow = lane & 15;    // fragment row (m for A, n for B)
    const int quad = lane >> 4;    // k-offset quad*8

    f32x4 acc[4][4];
    const f32x4 zero = {0.f, 0.f, 0.f, 0.f};
#pragma unroll
    for (int i = 0; i < 4; ++i)
#pragma unroll
        for (int j = 0; j < 4; ++j) acc[i][j] = zero;

    // staging map: thread t covers global row (t>>2), k-chunk (t&3)*8
    const int srow = tid >> 2;
    const int scol = (tid & 3) * 8;
    const ushort* Ag = A + (size_t)(m0 + srow) * K + scol;
    const ushort* Bg = BT + (size_t)(n0 + srow) * K + scol;
    ushort* AsT = As + tid * 8;        // byte offset tid*16
    ushort* BsT = Bs + tid * 8;

    for (int k0 = 0; k0 < K; k0 += 32) {
        ASYNC_COPY16(Ag + k0, AsT);                        // rows 0..63
        ASYNC_COPY16(Ag + k0 + (size_t)64 * K, AsT + 64 * 32);  // rows 64..127
        ASYNC_COPY16(Bg + k0, BsT);
        ASYNC_COPY16(Bg + k0 + (size_t)64 * K, BsT + 64 * 32);
        __syncthreads();   // compiler drains vmcnt(0) before s_barrier

        short8 a[4], b[4];
#pragma unroll
        for (int mt = 0; mt < 4; ++mt)
            a[mt] = *(const short8*)&As[(wm + mt * 16 + lrow) * 32 + quad * 8];
#pragma unroll
        for (int nt = 0; nt < 4; ++nt)
            b[nt] = *(const short8*)&Bs[(wn + nt * 16 + lrow) * 32 + quad * 8];
#pragma unroll
        for (int mt = 0; mt < 4; ++mt)
#pragma unroll
            for (int nt = 0; nt < 4; ++nt)
                acc[mt][nt] = __builtin_amdgcn_mfma_f32_16x16x32_bf16(
                    a[mt], b[nt], acc[mt][nt], 0, 0, 0);
        __syncthreads();
    }

    // C/D layout (verified m89): col = lane&15, row = (lane>>4)*4 + reg
    const int crow = quad * 4;
    const int ccol = lrow;
#pragma unroll
    for (int mt = 0; mt < 4; ++mt)
#pragma unroll
        for (int nt = 0; nt < 4; ++nt)
#pragma unroll
            for (int r = 0; r < 4; ++r)
                C[(size_t)(m0 + wm + mt * 16 + crow + r) * N +
                  n0 + wn + nt * 16 + ccol] = acc[mt][nt][r];
}

// ---------------------------------------------------------------------------
// RoPE in-place on fp32 Q [B,T,NH*HD] and K [B,T,NKV*HD]. (unchanged)
// ---------------------------------------------------------------------------
__global__ __launch_bounds__(256) void rope_kernel(float* __restrict__ Qb,
                                                   float* __restrict__ Kb) {
    const int idx = blockIdx.x * blockDim.x + threadIdx.x;
    const int i = idx & 63;
    const int head = (idx >> 6) % (NH + NKV);
    const int bt = idx / (64 * (NH + NKV));
    const int t = bt & (T_ - 1);
    const float inv = powf(10000.0f, -2.0f * (float)i / (float)HD);
    const float ang = (float)t * inv;
    const float c = cosf(ang);
    const float s = sinf(ang);
    float* p;
    if (head < NH) p = Qb + (size_t)bt * D_ + head * HD;
    else           p = Kb + (size_t)bt * KV_D + (head - NH) * HD;
    const float x1 = p[i];
    const float x2 = p[i + 64];
    p[i]      = x1 * c - x2 * s;
    p[i + 64] = x2 * c + x1 * s;
}

// ---------------------------------------------------------------------------
// Flash-style causal attention, fp32 compute (identical to round 1), except
// the epilogue writes Y as bf16 for the MFMA output projection.
// ---------------------------------------------------------------------------
#define QT 32
#define KT 32
#define LPAD 132

__global__ __launch_bounds__(128) void attn_kernel(const float* __restrict__ Qb,
                                                   const float* __restrict__ Kb,
                                                   const float* __restrict__ Vb,
                                                   ushort* __restrict__ Yb) {
    __shared__ float Qs[QT][LPAD];
    __shared__ float Ks[KT][LPAD];
    __shared__ float Vs[KT][LPAD];

    const int bh = blockIdx.x;
    const int qt = blockIdx.y;
    const int b = bh >> 4, h = bh & 15;
    const int kvh = h >> 2;
    const int q0 = qt * QT;
    const int tid = threadIdx.x;
    const int row = tid >> 2;
    const int quad = tid & 3;

    for (int idx = tid; idx < QT * (HD / 4); idx += 128) {
        const int r = idx >> 5, c4 = idx & 31;
        const float4 v = *(const float4*)&Qb[((size_t)(b * T_ + q0 + r)) * D_ + h * HD + c4 * 4];
        *(float4*)&Qs[r][c4 * 4] = v;
    }

    float m = -INFINITY, l = 0.f;
    float4 acc4[8];
#pragma unroll
    for (int j = 0; j < 8; ++j) acc4[j] = make_float4(0.f, 0.f, 0.f, 0.f);
    const float scale = 0.08838834764831845f;  // 1/sqrt(128)

    for (int kt = 0; kt <= qt; ++kt) {
        const int s0 = kt * KT;
        __syncthreads();
        for (int idx = tid; idx < KT * (HD / 4); idx += 128) {
            const int r = idx >> 5, c4 = idx & 31;
            const size_t base = ((size_t)(b * T_ + s0 + r)) * KV_D + kvh * HD + c4 * 4;
            *(float4*)&Ks[r][c4 * 4] = *(const float4*)&Kb[base];
            *(float4*)&Vs[r][c4 * 4] = *(const float4*)&Vb[base];
        }
        __syncthreads();

        float p[8];
        float sdot[8];
#pragma unroll
        for (int i = 0; i < 8; ++i) sdot[i] = 0.f;
#pragma unroll 2
        for (int d = 0; d < HD; d += 4) {
            const float4 qd = *(const float4*)&Qs[row][d];
#pragma unroll
            for (int i = 0; i < 8; ++i) {
                const float4 kd = *(const float4*)&Ks[quad + 4 * i][d];
                sdot[i] += qd.x * kd.x + qd.y * kd.y + qd.z * kd.z + qd.w * kd.w;
            }
        }
        float tmax = -INFINITY;
#pragma unroll
        for (int i = 0; i < 8; ++i) {
            const int c = quad + 4 * i;
            float sc = sdot[i] * scale;
            if (s0 + c > q0 + row) sc = -INFINITY;
            p[i] = sc;
            tmax = fmaxf(tmax, sc);
        }
        tmax = fmaxf(tmax, __shfl_xor(tmax, 1));
        tmax = fmaxf(tmax, __shfl_xor(tmax, 2));
        const float mnew = fmaxf(m, tmax);
        const float alpha = __expf(m - mnew);
        float sum = 0.f;
#pragma unroll
        for (int i = 0; i < 8; ++i) {
            p[i] = __expf(p[i] - mnew);
            sum += p[i];
        }
        sum += __shfl_xor(sum, 1);
        sum += __shfl_xor(sum, 2);
        l = l * alpha + sum;
        m = mnew;
#pragma unroll
        for (int j = 0; j < 8; ++j) {
            acc4[j].x *= alpha; acc4[j].y *= alpha; acc4[j].z *= alpha; acc4[j].w *= alpha;
        }
#pragma unroll
        for (int s = 0; s < KT; ++s) {
            const float pv = __shfl(p[s >> 2], s & 3, 4);
            const float4* vrow = (const float4*)&Vs[s][quad * 32];
#pragma unroll
            for (int j = 0; j < 8; ++j) {
                const float4 vv = vrow[j];
                acc4[j].x += pv * vv.x; acc4[j].y += pv * vv.y;
                acc4[j].z += pv * vv.z; acc4[j].w += pv * vv.w;
            }
        }
    }

    const float invl = 1.f / l;
    ushort* yrow = &Yb[((size_t)(b * T_ + q0 + row)) * D_ + h * HD + quad * 32];
    uint buf[16];
#pragma unroll
    for (int j = 0; j < 8; ++j) {
        const float4 o = acc4[j];
        buf[2 * j]     = (uint)f2b(o.x * invl) | ((uint)f2b(o.y * invl) << 16);
        buf[2 * j + 1] = (uint)f2b(o.z * invl) | ((uint)f2b(o.w * invl) << 16);
    }
#pragma unroll
    for (int jj = 0; jj < 4; ++jj)
        ((uint4*)yrow)[jj] = ((uint4*)buf)[jj];
}

// ---------------------------------------------------------------------------
extern "C" void kernel_launch(void* const* d_in, const int* in_sizes, int n_in,
                              void* d_out, int out_size, void* d_ws, size_t ws_size,
                              hipStream_t stream) {
    const float* x  = (const float*)d_in[0];
    const float* Wq = (const float*)d_in[1];
    const float* Wk = (const float*)d_in[2];
    const float* Wv = (const float*)d_in[3];
    const float* Wo = (const float*)d_in[4];
    float* out = (float*)d_out;

    // Workspace layout (79.7 MB; round-1 footprint was 83.9 MB so ws_size fits):
    //   Qf fp32 [4096,2048] | Kf fp32 [4096,512] | Vf fp32 [4096,512]
    //   xb bf16 [4096,2048]  (aliased by Yb bf16 after gemm-V)
    //   WqT bf16 [2048,2048] (aliased by WoT after gemm-Q)
    //   WkT bf16 [512,2048] | WvT bf16 [512,2048]
    char* w = (char*)d_ws;
    float*  Qf  = (float*)w;                    w += (size_t)4096 * 2048 * 4;
    float*  Kf  = (float*)w;                    w += (size_t)4096 * 512 * 4;
    float*  Vf  = (float*)w;                    w += (size_t)4096 * 512 * 4;
    ushort* xb  = (ushort*)w;                   w += (size_t)4096 * 2048 * 2;
    ushort* WqT = (ushort*)w;                   w += (size_t)2048 * 2048 * 2;
    ushort* WkT = (ushort*)w;                   w += (size_t)512 * 2048 * 2;
    ushort* WvT = (ushort*)w;                   w += (size_t)512 * 2048 * 2;
    ushort* Yb  = xb;    // alias: xb dead after gemm-V (stream-serial)
    ushort* WoT = WqT;   // alias: WqT dead after gemm-Q (stream-serial)

    const int M = B_ * T_;  // 4096
    dim3 blk(256);

    // prep: cast x, transpose+cast weights needed before their GEMMs
    cast_f32_bf16<<<(M * D_ / 4 + 255) / 256, blk, 0, stream>>>(x, xb, M * D_ / 4);
    transpose_cast<<<dim3(D_ / 32, D_ / 32), blk, 0, stream>>>(Wq, WqT, D_, D_);
    transpose_cast<<<dim3(KV_D / 32, D_ / 32), blk, 0, stream>>>(Wk, WkT, D_, KV_D);
    transpose_cast<<<dim3(KV_D / 32, D_ / 32), blk, 0, stream>>>(Wv, WvT, D_, KV_D);

    // projections (bf16 MFMA, fp32 out)
    gemm_bf16<<<dim3(D_ / 128, M / 128), blk, 0, stream>>>(xb, WqT, Qf, M, D_, D_);
    gemm_bf16<<<dim3(KV_D / 128, M / 128), blk, 0, stream>>>(xb, WkT, Kf, M, KV_D, D_);
    gemm_bf16<<<dim3(KV_D / 128, M / 128), blk, 0, stream>>>(xb, WvT, Vf, M, KV_D, D_);

    // Wo transpose reuses WqT space (safe after gemm-Q on the same stream)
    transpose_cast<<<dim3(D_ / 32, D_ / 32), blk, 0, stream>>>(Wo, WoT, D_, D_);

    const int rope_total = B_ * T_ * (NH + NKV) * 64;
    rope_kernel<<<rope_total / 256, blk, 0, stream>>>(Qf, Kf);

    attn_kernel<<<dim3(B_ * NH, T_ / QT), dim3(128), 0, stream>>>(Qf, Kf, Vf, Yb);

    // output projection: bf16 Y x bf16 Wo^T -> fp32 out
    gemm_bf16<<<dim3(D_ / 128, M / 128), blk, 0, stream>>>(Yb, WoT, out, M, D_, D_);
}

// Round 3
// 427.385 us; speedup vs baseline: 5.8464x; 2.7795x over previous
//
#include <hip/hip_runtime.h>
#include <math.h>

#define B_ 4
#define T_ 1024
#define D_ 2048
#define NH 16
#define NKV 4
#define HD 128
#define KV_D 512   // NKV * HD

typedef __attribute__((ext_vector_type(8))) short short8;   // 8 x bf16 (4 VGPRs)
typedef __attribute__((ext_vector_type(4))) float f32x4;    // MFMA accumulator

// fp32 -> bf16 round-to-nearest-even (finite inputs)
__device__ __forceinline__ ushort f2b(float f) {
    unsigned u = __float_as_uint(f);
    return (ushort)((u + 0x7fffu + ((u >> 16) & 1u)) >> 16);
}

#define ASYNC_COPY16(g, l)                                                  \
    __builtin_amdgcn_global_load_lds(                                       \
        (const __attribute__((address_space(1))) void*)(g),                 \
        (__attribute__((address_space(3))) void*)(l), 16, 0, 0)

// ---------------------------------------------------------------------------
// cast x (fp32) -> bf16, 4 elements/thread
// ---------------------------------------------------------------------------
__global__ __launch_bounds__(256) void cast_f32_bf16(const float* __restrict__ in,
                                                     ushort* __restrict__ out, int n4) {
    const int i = blockIdx.x * blockDim.x + threadIdx.x;
    if (i >= n4) return;
    const float4 v = ((const float4*)in)[i];
    ushort4 u;
    u.x = f2b(v.x); u.y = f2b(v.y); u.z = f2b(v.z); u.w = f2b(v.w);
    ((ushort4*)out)[i] = u;
}

// ---------------------------------------------------------------------------
// W [K][N] fp32 -> WT [N][K] bf16
// ---------------------------------------------------------------------------
__global__ __launch_bounds__(256) void transpose_cast(const float* __restrict__ W,
                                                      ushort* __restrict__ WT,
                                                      int K, int N) {
    __shared__ float tile[32][33];
    const int n0 = blockIdx.x * 32, k0 = blockIdx.y * 32;
    const int tx = threadIdx.x & 31, ty = threadIdx.x >> 5;  // 32 x 8
    for (int i = ty; i < 32; i += 8)
        tile[i][tx] = W[(size_t)(k0 + i) * N + n0 + tx];
    __syncthreads();
    for (int i = ty; i < 32; i += 8)
        WT[(size_t)(n0 + i) * K + k0 + tx] = f2b(tile[tx][i]);
}

// ---------------------------------------------------------------------------
// V [B*T][KV_D] fp32 -> Vt [B][NKV][HD][T] bf16 (d-major for attention PV)
// ---------------------------------------------------------------------------
__global__ __launch_bounds__(256) void transpose_v(const float* __restrict__ Vf,
                                                   ushort* __restrict__ Vt) {
    __shared__ float tile[32][33];
    const int bkv = blockIdx.x;
    const int b = bkv >> 2, kv = bkv & 3;
    const int t0 = blockIdx.y * 32, d0 = blockIdx.z * 32;
    const int tx = threadIdx.x & 31, ty = threadIdx.x >> 5;  // 32 x 8
    for (int i = ty; i < 32; i += 8)
        tile[i][tx] = Vf[(size_t)(b * T_ + t0 + i) * KV_D + kv * HD + d0 + tx];
    __syncthreads();
    for (int i = ty; i < 32; i += 8)
        Vt[((size_t)((b * NKV + kv) * HD + d0 + i)) * T_ + t0 + tx] = f2b(tile[tx][i]);
}

// ---------------------------------------------------------------------------
// m97-style bf16 MFMA GEMM: C[M,N] fp32 = A[M,K] bf16 x BT[N,K] bf16.
// 128x128 tile, BK=32, 4 waves, global_load_lds width-16. (unchanged, verified)
// ---------------------------------------------------------------------------
__global__ __launch_bounds__(256) void gemm_bf16(const ushort* __restrict__ A,
                                                 const ushort* __restrict__ BT,
                                                 float* __restrict__ C,
                                                 int M, int N, int K) {
    __shared__ ushort As[128 * 32];
    __shared__ ushort Bs[128 * 32];
    const int tid = threadIdx.x;
    const int m0 = blockIdx.y * 128, n0 = blockIdx.x * 128;
    const int wave = tid >> 6, lane = tid & 63;
    const int wm = (wave >> 1) * 64, wn = (wave & 1) * 64;
    const int lrow = lane & 15;
    const int quad = lane >> 4;

    f32x4 acc[4][4];
    const f32x4 zero = {0.f, 0.f, 0.f, 0.f};
#pragma unroll
    for (int i = 0; i < 4; ++i)
#pragma unroll
        for (int j = 0; j < 4; ++j) acc[i][j] = zero;

    const int srow = tid >> 2;
    const int scol = (tid & 3) * 8;
    const ushort* Ag = A + (size_t)(m0 + srow) * K + scol;
    const ushort* Bg = BT + (size_t)(n0 + srow) * K + scol;
    ushort* AsT = As + tid * 8;
    ushort* BsT = Bs + tid * 8;

    for (int k0 = 0; k0 < K; k0 += 32) {
        ASYNC_COPY16(Ag + k0, AsT);
        ASYNC_COPY16(Ag + k0 + (size_t)64 * K, AsT + 64 * 32);
        ASYNC_COPY16(Bg + k0, BsT);
        ASYNC_COPY16(Bg + k0 + (size_t)64 * K, BsT + 64 * 32);
        __syncthreads();

        short8 a[4], b[4];
#pragma unroll
        for (int mt = 0; mt < 4; ++mt)
            a[mt] = *(const short8*)&As[(wm + mt * 16 + lrow) * 32 + quad * 8];
#pragma unroll
        for (int nt = 0; nt < 4; ++nt)
            b[nt] = *(const short8*)&Bs[(wn + nt * 16 + lrow) * 32 + quad * 8];
#pragma unroll
        for (int mt = 0; mt < 4; ++mt)
#pragma unroll
            for (int nt = 0; nt < 4; ++nt)
                acc[mt][nt] = __builtin_amdgcn_mfma_f32_16x16x32_bf16(
                    a[mt], b[nt], acc[mt][nt], 0, 0, 0);
        __syncthreads();
    }

    const int crow = quad * 4;
    const int ccol = lrow;
#pragma unroll
    for (int mt = 0; mt < 4; ++mt)
#pragma unroll
        for (int nt = 0; nt < 4; ++nt)
#pragma unroll
            for (int r = 0; r < 4; ++r)
                C[(size_t)(m0 + wm + mt * 16 + crow + r) * N +
                  n0 + wn + nt * 16 + ccol] = acc[mt][nt][r];
}

// ---------------------------------------------------------------------------
// RoPE: read fp32 Q/K (post-GEMM), write bf16 Q (pre-scaled by 1/sqrt(HD))
// and bf16 K. One thread per (bt, head, i<64).
// ---------------------------------------------------------------------------
__global__ __launch_bounds__(256) void rope_cast(const float* __restrict__ Qf,
                                                 const float* __restrict__ Kf,
                                                 ushort* __restrict__ Qb,
                                                 ushort* __restrict__ Kb) {
    const int idx = blockIdx.x * blockDim.x + threadIdx.x;
    const int i = idx & 63;
    const int head = (idx >> 6) % (NH + NKV);
    const int bt = idx / (64 * (NH + NKV));
    const int t = bt & (T_ - 1);
    const float inv = powf(10000.0f, -2.0f * (float)i / (float)HD);
    const float ang = (float)t * inv;
    const float c = cosf(ang), s = sinf(ang);
    if (head < NH) {   // wave-uniform branch (64 consecutive idx share head)
        const size_t base = (size_t)bt * D_ + head * HD;
        const float x1 = Qf[base + i], x2 = Qf[base + i + 64];
        const float sc = 0.08838834764831845f;  // 1/sqrt(128) folded into Q
        Qb[base + i]      = f2b((x1 * c - x2 * s) * sc);
        Qb[base + i + 64] = f2b((x2 * c + x1 * s) * sc);
    } else {
        const size_t base = (size_t)bt * KV_D + (head - NH) * HD;
        const float x1 = Kf[base + i], x2 = Kf[base + i + 64];
        Kb[base + i]      = f2b(x1 * c - x2 * s);
        Kb[base + i + 64] = f2b(x2 * c + x1 * s);
    }
}

// ---------------------------------------------------------------------------
// MFMA flash attention. WG = 256 thr (4 waves), 64 Q-rows per WG (16/wave,
// Q in registers as A-fragments). K-loop over 64-wide S tiles:
//   S = Q K^T (16 MFMAs) -> online softmax in C-layout (16-lane shfl stats)
//   -> P via per-wave LDS round-trip to A-layout -> O += P V (16 MFMAs).
// V is staged from the pre-transposed Vt [HD][T] so B-fragments are
// contiguous. LDS strides 136/72 ushorts => dword stride = 4 mod 32 (bank-
// minimal b128). LDS = 45056 B -> 3 WG/CU.
// ---------------------------------------------------------------------------
__global__ __launch_bounds__(256) void attn_mfma(const ushort* __restrict__ Qb,
                                                 const ushort* __restrict__ Kb,
                                                 const ushort* __restrict__ Vt,
                                                 ushort* __restrict__ Yb) {
    __shared__ ushort Ks[64][136];       // [s][d]
    __shared__ ushort Vs[128][72];       // [d][s]
    __shared__ ushort Ps[4][16][72];     // per-wave P tile [qrow][s]

    const int bh = blockIdx.x;
    const int qt = blockIdx.y;
    const int b = bh >> 4, h = bh & 15;
    const int kvh = h >> 2;
    const int q0 = qt * 64;
    const int tid = threadIdx.x;
    const int wave = tid >> 6, lane = tid & 63;
    const int ln = lane & 15, quad = lane >> 4;

    // Q fragments (A-layout: m=ln, k=quad*8+j), rows q0 + wave*16 + ln
    short8 qf[4];
    {
        const ushort* qp = Qb + ((size_t)(b * T_ + q0 + wave * 16 + ln)) * D_ + h * HD + quad * 8;
#pragma unroll
        for (int f = 0; f < 4; ++f) qf[f] = *(const short8*)(qp + f * 32);
    }

    f32x4 acc[8];
    const f32x4 zero = {0.f, 0.f, 0.f, 0.f};
#pragma unroll
    for (int j = 0; j < 8; ++j) acc[j] = zero;
    float m_r[4], l_r[4];
#pragma unroll
    for (int r = 0; r < 4; ++r) { m_r[r] = -INFINITY; l_r[r] = 0.f; }

    const int qrow = q0 + wave * 16 + quad * 4;   // C-layout row base (+r)

    for (int kt = 0; kt <= qt; ++kt) {
        const int s0 = kt * 64;
        __syncthreads();   // protect previous-iteration Ks/Vs reads
        // stage K tile [64][128]: 1024 16B chunks, coalesced
#pragma unroll
        for (int c = 0; c < 4; ++c) {
            const int cid = tid + 256 * c;
            const int s = cid >> 4, ch = cid & 15;
            *(short8*)&Ks[s][ch * 8] =
                *(const short8*)&Kb[((size_t)(b * T_ + s0 + s)) * KV_D + kvh * HD + ch * 8];
        }
        // stage V^T tile [128][64]
#pragma unroll
        for (int c = 0; c < 4; ++c) {
            const int cid = tid + 256 * c;
            const int d = cid >> 3, ch = cid & 7;
            *(short8*)&Vs[d][ch * 8] =
                *(const short8*)&Vt[((size_t)((b * NKV + kvh) * HD + d)) * T_ + s0 + ch * 8];
        }
        __syncthreads();

        // S = Q K^T : 4 col-tiles of 16 (B-frag: n=ln, k=quad*8+j from Ks row)
        float sc[4][4];
#pragma unroll
        for (int ct = 0; ct < 4; ++ct) {
            f32x4 s4 = zero;
#pragma unroll
            for (int f = 0; f < 4; ++f)
                s4 = __builtin_amdgcn_mfma_f32_16x16x32_bf16(
                    qf[f], *(const short8*)&Ks[ct * 16 + ln][f * 32 + quad * 8], s4, 0, 0, 0);
#pragma unroll
            for (int r = 0; r < 4; ++r) sc[ct][r] = s4[r];
        }
        // causal mask: only the diagonal tile needs it (kt<qt => s_max < q0)
        if (kt == qt) {
#pragma unroll
            for (int ct = 0; ct < 4; ++ct)
#pragma unroll
                for (int r = 0; r < 4; ++r)
                    if (s0 + ct * 16 + ln > qrow + r) sc[ct][r] = -INFINITY;
        }
        // online softmax, per C-layout row quad*4+r (stats across 16-lane group)
        float alpha[4];
#pragma unroll
        for (int r = 0; r < 4; ++r) {
            float mx = fmaxf(fmaxf(sc[0][r], sc[1][r]), fmaxf(sc[2][r], sc[3][r]));
            mx = fmaxf(mx, __shfl_xor(mx, 1));
            mx = fmaxf(mx, __shfl_xor(mx, 2));
            mx = fmaxf(mx, __shfl_xor(mx, 4));
            mx = fmaxf(mx, __shfl_xor(mx, 8));
            const float mnew = fmaxf(m_r[r], mx);
            alpha[r] = __expf(m_r[r] - mnew);   // m=-inf -> 0
            m_r[r] = mnew;
#pragma unroll
            for (int ct = 0; ct < 4; ++ct) sc[ct][r] = __expf(sc[ct][r] - mnew);
            float sum = (sc[0][r] + sc[1][r]) + (sc[2][r] + sc[3][r]);
            sum += __shfl_xor(sum, 1);
            sum += __shfl_xor(sum, 2);
            sum += __shfl_xor(sum, 4);
            sum += __shfl_xor(sum, 8);
            l_r[r] = l_r[r] * alpha[r] + sum;
        }
        // P (C-layout) -> per-wave LDS (no barrier: wave-private, in-order DS)
#pragma unroll
        for (int ct = 0; ct < 4; ++ct)
#pragma unroll
            for (int r = 0; r < 4; ++r)
                Ps[wave][quad * 4 + r][ct * 16 + ln] = f2b(sc[ct][r]);
        // rescale O
#pragma unroll
        for (int j = 0; j < 8; ++j)
#pragma unroll
            for (int r = 0; r < 4; ++r) acc[j][r] *= alpha[r];
        // P as A-fragments (m=ln, k=quad*8+j), two 32-wide k slices
        const short8 pa0 = *(const short8*)&Ps[wave][ln][quad * 8];
        const short8 pa1 = *(const short8*)&Ps[wave][ln][32 + quad * 8];
#pragma unroll
        for (int j = 0; j < 8; ++j) {
            acc[j] = __builtin_amdgcn_mfma_f32_16x16x32_bf16(
                pa0, *(const short8*)&Vs[j * 16 + ln][quad * 8], acc[j], 0, 0, 0);
            acc[j] = __builtin_amdgcn_mfma_f32_16x16x32_bf16(
                pa1, *(const short8*)&Vs[j * 16 + ln][32 + quad * 8], acc[j], 0, 0, 0);
        }
    }

    float invl[4];
#pragma unroll
    for (int r = 0; r < 4; ++r) invl[r] = 1.f / l_r[r];
    ushort* yb = Yb + ((size_t)(b * T_ + qrow)) * D_ + h * HD + ln;
#pragma unroll
    for (int r = 0; r < 4; ++r)
#pragma unroll
        for (int j = 0; j < 8; ++j)
            yb[(size_t)r * D_ + j * 16] = f2b(acc[j][r] * invl[r]);
}

// ---------------------------------------------------------------------------
extern "C" void kernel_launch(void* const* d_in, const int* in_sizes, int n_in,
                              void* d_out, int out_size, void* d_ws, size_t ws_size,
                              hipStream_t stream) {
    const float* x  = (const float*)d_in[0];
    const float* Wq = (const float*)d_in[1];
    const float* Wk = (const float*)d_in[2];
    const float* Wv = (const float*)d_in[3];
    const float* Wo = (const float*)d_in[4];
    float* out = (float*)d_out;

    // Workspace (83.9 MB total, same footprint as round 1):
    char* w = (char*)d_ws;
    float*  Qf   = (float*)w;   w += (size_t)4096 * 2048 * 4;   // 33.55 MB
    float*  Kf   = (float*)w;   w += (size_t)4096 * 512 * 4;    //  8.39 MB
    float*  Vf   = (float*)w;   w += (size_t)4096 * 512 * 4;    //  8.39 MB
    ushort* xb   = (ushort*)w;  w += (size_t)4096 * 2048 * 2;   // 16.78 MB
    ushort* WqT  = (ushort*)w;  w += (size_t)2048 * 2048 * 2;   //  8.39 MB
    ushort* WkT  = (ushort*)w;  w += (size_t)512 * 2048 * 2;    //  2.10 MB
    ushort* WvT  = (ushort*)w;  w += (size_t)512 * 2048 * 2;    //  2.10 MB
    ushort* Kb16 = (ushort*)w;  w += (size_t)4096 * 512 * 2;    //  4.19 MB
    // stream-serial aliases:
    ushort* Qb16 = xb;           // xb dead after gemm-V; rope_cast runs after
    ushort* Vt   = WkT;          // WkT+WvT (4.19 MB) dead after gemm-V
    ushort* Yb   = (ushort*)Qf;  // Qf dead after rope_cast
    ushort* WoT  = WqT;          // WqT dead after gemm-Q

    const int M = B_ * T_;  // 4096
    dim3 blk(256);

    cast_f32_bf16<<<(M * D_ / 4 + 255) / 256, blk, 0, stream>>>(x, xb, M * D_ / 4);
    transpose_cast<<<dim3(D_ / 32, D_ / 32), blk, 0, stream>>>(Wq, WqT, D_, D_);
    transpose_cast<<<dim3(KV_D / 32, D_ / 32), blk, 0, stream>>>(Wk, WkT, D_, KV_D);
    transpose_cast<<<dim3(KV_D / 32, D_ / 32), blk, 0, stream>>>(Wv, WvT, D_, KV_D);

    gemm_bf16<<<dim3(D_ / 128, M / 128), blk, 0, stream>>>(xb, WqT, Qf, M, D_, D_);
    gemm_bf16<<<dim3(KV_D / 128, M / 128), blk, 0, stream>>>(xb, WkT, Kf, M, KV_D, D_);
    gemm_bf16<<<dim3(KV_D / 128, M / 128), blk, 0, stream>>>(xb, WvT, Vf, M, KV_D, D_);

    transpose_cast<<<dim3(D_ / 32, D_ / 32), blk, 0, stream>>>(Wo, WoT, D_, D_);

    const int rope_total = B_ * T_ * (NH + NKV) * 64;
    rope_cast<<<rope_total / 256, blk, 0, stream>>>(Qf, Kf, Qb16, Kb16);

    transpose_v<<<dim3(B_ * NKV, T_ / 32, HD / 32), blk, 0, stream>>>(Vf, Vt);

    attn_mfma<<<dim3(B_ * NH, T_ / 64), blk, 0, stream>>>(Qb16, Kb16, Vt, Yb);

    gemm_bf16<<<dim3(D_ / 128, M / 128), blk, 0, stream>>>(Yb, WoT, out, M, D_, D_);
}

// Round 4
// 350.986 us; speedup vs baseline: 7.1190x; 1.2177x over previous
//
#include <hip/hip_runtime.h>
#include <math.h>

#define B_ 4
#define T_ 1024
#define D_ 2048
#define NH 16
#define NKV 4
#define HD 128
#define KV_D 512    // NKV * HD
#define QKV_W 3072  // D_ + 2*KV_D : fused projection width

typedef __attribute__((ext_vector_type(8))) short short8;   // 8 x bf16 (4 VGPRs)
typedef __attribute__((ext_vector_type(4))) float f32x4;    // MFMA accumulator

// fp32 -> bf16 round-to-nearest-even (finite inputs)
__device__ __forceinline__ ushort f2b(float f) {
    unsigned u = __float_as_uint(f);
    return (ushort)((u + 0x7fffu + ((u >> 16) & 1u)) >> 16);
}
__device__ __forceinline__ float b2f(ushort u) {
    return __uint_as_float((unsigned)u << 16);
}

#define ASYNC_COPY16(g, l)                                                  \
    __builtin_amdgcn_global_load_lds(                                       \
        (const __attribute__((address_space(1))) void*)(g),                 \
        (__attribute__((address_space(3))) void*)(l), 16, 0, 0)

// ---------------------------------------------------------------------------
// cast x (fp32) -> bf16, 4 elements/thread
// ---------------------------------------------------------------------------
__global__ __launch_bounds__(256) void cast_f32_bf16(const float* __restrict__ in,
                                                     ushort* __restrict__ out, int n4) {
    const int i = blockIdx.x * blockDim.x + threadIdx.x;
    if (i >= n4) return;
    const float4 v = ((const float4*)in)[i];
    ushort4 u;
    u.x = f2b(v.x); u.y = f2b(v.y); u.z = f2b(v.z); u.w = f2b(v.w);
    ((ushort4*)out)[i] = u;
}

// ---------------------------------------------------------------------------
// W [K][N] fp32 -> WT [N][K] bf16 (WT may be a row-offset into WqkvT)
// ---------------------------------------------------------------------------
__global__ __launch_bounds__(256) void transpose_cast(const float* __restrict__ W,
                                                      ushort* __restrict__ WT,
                                                      int K, int N) {
    __shared__ float tile[32][33];
    const int n0 = blockIdx.x * 32, k0 = blockIdx.y * 32;
    const int tx = threadIdx.x & 31, ty = threadIdx.x >> 5;  // 32 x 8
    for (int i = ty; i < 32; i += 8)
        tile[i][tx] = W[(size_t)(k0 + i) * N + n0 + tx];
    __syncthreads();
    for (int i = ty; i < 32; i += 8)
        WT[(size_t)(n0 + i) * K + k0 + tx] = f2b(tile[tx][i]);
}

// ---------------------------------------------------------------------------
// V columns of QKV (bf16) -> Vt [B][NKV][HD][T] bf16 (d-major for PV MFMA)
// ---------------------------------------------------------------------------
__global__ __launch_bounds__(256) void transpose_v16(const ushort* __restrict__ QKV,
                                                     ushort* __restrict__ Vt) {
    __shared__ ushort tile[32][34];
    const int bkv = blockIdx.x;
    const int b = bkv >> 2, kv = bkv & 3;
    const int t0 = blockIdx.y * 32, d0 = blockIdx.z * 32;
    const int tx = threadIdx.x & 31, ty = threadIdx.x >> 5;  // 32 x 8
    for (int i = ty; i < 32; i += 8)
        tile[i][tx] = QKV[(size_t)(b * T_ + t0 + i) * QKV_W + D_ + KV_D + kv * HD + d0 + tx];
    __syncthreads();
    for (int i = ty; i < 32; i += 8)
        Vt[((size_t)((b * NKV + kv) * HD + d0 + i)) * T_ + t0 + tx] = tile[tx][i];
}

// ---------------------------------------------------------------------------
// m97-style bf16 MFMA GEMM: C[M,N] = A[M,K] bf16 x BT[N,K] bf16.
// 128x128 tile, BK=32, 4 waves, global_load_lds width-16.
// OUT_BF16 selects fp32 or bf16 C.
// ---------------------------------------------------------------------------
template <bool OUT_BF16>
__global__ __launch_bounds__(256) void gemm_bf16_t(const ushort* __restrict__ A,
                                                   const ushort* __restrict__ BT,
                                                   void* __restrict__ Cv,
                                                   int M, int N, int K) {
    __shared__ ushort As[128 * 32];
    __shared__ ushort Bs[128 * 32];
    const int tid = threadIdx.x;
    const int m0 = blockIdx.y * 128, n0 = blockIdx.x * 128;
    const int wave = tid >> 6, lane = tid & 63;
    const int wm = (wave >> 1) * 64, wn = (wave & 1) * 64;
    const int lrow = lane & 15;
    const int quad = lane >> 4;

    f32x4 acc[4][4];
    const f32x4 zero = {0.f, 0.f, 0.f, 0.f};
#pragma unroll
    for (int i = 0; i < 4; ++i)
#pragma unroll
        for (int j = 0; j < 4; ++j) acc[i][j] = zero;

    const int srow = tid >> 2;
    const int scol = (tid & 3) * 8;
    const ushort* Ag = A + (size_t)(m0 + srow) * K + scol;
    const ushort* Bg = BT + (size_t)(n0 + srow) * K + scol;
    ushort* AsT = As + tid * 8;
    ushort* BsT = Bs + tid * 8;

    for (int k0 = 0; k0 < K; k0 += 32) {
        ASYNC_COPY16(Ag + k0, AsT);
        ASYNC_COPY16(Ag + k0 + (size_t)64 * K, AsT + 64 * 32);
        ASYNC_COPY16(Bg + k0, BsT);
        ASYNC_COPY16(Bg + k0 + (size_t)64 * K, BsT + 64 * 32);
        __syncthreads();

        short8 a[4], b[4];
#pragma unroll
        for (int mt = 0; mt < 4; ++mt)
            a[mt] = *(const short8*)&As[(wm + mt * 16 + lrow) * 32 + quad * 8];
#pragma unroll
        for (int nt = 0; nt < 4; ++nt)
            b[nt] = *(const short8*)&Bs[(wn + nt * 16 + lrow) * 32 + quad * 8];
#pragma unroll
        for (int mt = 0; mt < 4; ++mt)
#pragma unroll
            for (int nt = 0; nt < 4; ++nt)
                acc[mt][nt] = __builtin_amdgcn_mfma_f32_16x16x32_bf16(
                    a[mt], b[nt], acc[mt][nt], 0, 0, 0);
        __syncthreads();
    }

    // C/D layout (verified m89): col = lane&15, row = (lane>>4)*4 + reg
    const int crow = quad * 4;
    const int ccol = lrow;
#pragma unroll
    for (int mt = 0; mt < 4; ++mt)
#pragma unroll
        for (int nt = 0; nt < 4; ++nt)
#pragma unroll
            for (int r = 0; r < 4; ++r) {
                const size_t idx = (size_t)(m0 + wm + mt * 16 + crow + r) * N +
                                   n0 + wn + nt * 16 + ccol;
                if (OUT_BF16) ((ushort*)Cv)[idx] = f2b(acc[mt][nt][r]);
                else          ((float*)Cv)[idx] = acc[mt][nt][r];
            }
}

// ---------------------------------------------------------------------------
// RoPE in-place on the bf16 QKV buffer [B*T][3072]. Heads 0..15 = Q (also
// folds 1/sqrt(HD) into Q), heads 16..19 = K. V untouched. One thread per
// (bt, head, i<64); branch is wave-uniform (64 consecutive idx share head).
// ---------------------------------------------------------------------------
__global__ __launch_bounds__(256) void rope_inplace(ushort* __restrict__ QKV) {
    const int idx = blockIdx.x * blockDim.x + threadIdx.x;
    const int i = idx & 63;
    const int tmp = idx >> 6;
    const int head = tmp % (NH + NKV);
    const int bt = tmp / (NH + NKV);
    const int t = bt & (T_ - 1);
    const float inv = powf(10000.0f, -2.0f * (float)i / (float)HD);
    const float ang = (float)t * inv;
    const float c = cosf(ang), s = sinf(ang);
    const bool isQ = head < NH;
    const size_t base = (size_t)bt * QKV_W +
                        (isQ ? head * HD : D_ + (head - NH) * HD);
    const float sc = isQ ? 0.08838834764831845f : 1.0f;  // 1/sqrt(128) into Q
    const float x1 = b2f(QKV[base + i]);
    const float x2 = b2f(QKV[base + i + 64]);
    QKV[base + i]      = f2b((x1 * c - x2 * s) * sc);
    QKV[base + i + 64] = f2b((x2 * c + x1 * s) * sc);
}

// ---------------------------------------------------------------------------
// MFMA flash attention (round-3 verified structure). Q/K read directly from
// the roped QKV buffer (row stride 3072); V from pre-transposed Vt [HD][T].
// WG = 256 thr (4 waves), 64 Q-rows/WG. LDS = 45056 B -> 3 WG/CU.
// ---------------------------------------------------------------------------
__global__ __launch_bounds__(256) void attn_mfma(const ushort* __restrict__ QKV,
                                                 const ushort* __restrict__ Vt,
                                                 ushort* __restrict__ Yb) {
    __shared__ ushort Ks[64][136];       // [s][d]
    __shared__ ushort Vs[128][72];       // [d][s]
    __shared__ ushort Ps[4][16][72];     // per-wave P tile [qrow][s]

    const int bh = blockIdx.x;
    const int qt = blockIdx.y;
    const int b = bh >> 4, h = bh & 15;
    const int kvh = h >> 2;
    const int q0 = qt * 64;
    const int tid = threadIdx.x;
    const int wave = tid >> 6, lane = tid & 63;
    const int ln = lane & 15, quad = lane >> 4;

    // Q fragments (A-layout: m=ln, k=quad*8+j), rows q0 + wave*16 + ln
    short8 qf[4];
    {
        const ushort* qp = QKV + ((size_t)(b * T_ + q0 + wave * 16 + ln)) * QKV_W + h * HD + quad * 8;
#pragma unroll
        for (int f = 0; f < 4; ++f) qf[f] = *(const short8*)(qp + f * 32);
    }

    f32x4 acc[8];
    const f32x4 zero = {0.f, 0.f, 0.f, 0.f};
#pragma unroll
    for (int j = 0; j < 8; ++j) acc[j] = zero;
    float m_r[4], l_r[4];
#pragma unroll
    for (int r = 0; r < 4; ++r) { m_r[r] = -INFINITY; l_r[r] = 0.f; }

    const int qrow = q0 + wave * 16 + quad * 4;   // C-layout row base (+r)

    for (int kt = 0; kt <= qt; ++kt) {
        const int s0 = kt * 64;
        __syncthreads();   // protect previous-iteration Ks/Vs reads
        // stage K tile [64][128] from QKV cols D_ + kvh*HD
#pragma unroll
        for (int c = 0; c < 4; ++c) {
            const int cid = tid + 256 * c;
            const int s = cid >> 4, ch = cid & 15;
            *(short8*)&Ks[s][ch * 8] =
                *(const short8*)&QKV[((size_t)(b * T_ + s0 + s)) * QKV_W + D_ + kvh * HD + ch * 8];
        }
        // stage V^T tile [128][64]
#pragma unroll
        for (int c = 0; c < 4; ++c) {
            const int cid = tid + 256 * c;
            const int d = cid >> 3, ch = cid & 7;
            *(short8*)&Vs[d][ch * 8] =
                *(const short8*)&Vt[((size_t)((b * NKV + kvh) * HD + d)) * T_ + s0 + ch * 8];
        }
        __syncthreads();

        // S = Q K^T : 4 col-tiles of 16
        float sc[4][4];
#pragma unroll
        for (int ct = 0; ct < 4; ++ct) {
            f32x4 s4 = zero;
#pragma unroll
            for (int f = 0; f < 4; ++f)
                s4 = __builtin_amdgcn_mfma_f32_16x16x32_bf16(
                    qf[f], *(const short8*)&Ks[ct * 16 + ln][f * 32 + quad * 8], s4, 0, 0, 0);
#pragma unroll
            for (int r = 0; r < 4; ++r) sc[ct][r] = s4[r];
        }
        // causal mask: only the diagonal tile needs it
        if (kt == qt) {
#pragma unroll
            for (int ct = 0; ct < 4; ++ct)
#pragma unroll
                for (int r = 0; r < 4; ++r)
                    if (s0 + ct * 16 + ln > qrow + r) sc[ct][r] = -INFINITY;
        }
        // online softmax per C-layout row (stats across 16-lane group)
        float alpha[4];
#pragma unroll
        for (int r = 0; r < 4; ++r) {
            float mx = fmaxf(fmaxf(sc[0][r], sc[1][r]), fmaxf(sc[2][r], sc[3][r]));
            mx = fmaxf(mx, __shfl_xor(mx, 1));
            mx = fmaxf(mx, __shfl_xor(mx, 2));
            mx = fmaxf(mx, __shfl_xor(mx, 4));
            mx = fmaxf(mx, __shfl_xor(mx, 8));
            const float mnew = fmaxf(m_r[r], mx);
            alpha[r] = __expf(m_r[r] - mnew);
            m_r[r] = mnew;
#pragma unroll
            for (int ct = 0; ct < 4; ++ct) sc[ct][r] = __expf(sc[ct][r] - mnew);
            float sum = (sc[0][r] + sc[1][r]) + (sc[2][r] + sc[3][r]);
            sum += __shfl_xor(sum, 1);
            sum += __shfl_xor(sum, 2);
            sum += __shfl_xor(sum, 4);
            sum += __shfl_xor(sum, 8);
            l_r[r] = l_r[r] * alpha[r] + sum;
        }
        // P (C-layout) -> per-wave LDS (wave-private, no barrier needed)
#pragma unroll
        for (int ct = 0; ct < 4; ++ct)
#pragma unroll
            for (int r = 0; r < 4; ++r)
                Ps[wave][quad * 4 + r][ct * 16 + ln] = f2b(sc[ct][r]);
        // rescale O
#pragma unroll
        for (int j = 0; j < 8; ++j)
#pragma unroll
            for (int r = 0; r < 4; ++r) acc[j][r] *= alpha[r];
        // P as A-fragments, two 32-wide k slices
        const short8 pa0 = *(const short8*)&Ps[wave][ln][quad * 8];
        const short8 pa1 = *(const short8*)&Ps[wave][ln][32 + quad * 8];
#pragma unroll
        for (int j = 0; j < 8; ++j) {
            acc[j] = __builtin_amdgcn_mfma_f32_16x16x32_bf16(
                pa0, *(const short8*)&Vs[j * 16 + ln][quad * 8], acc[j], 0, 0, 0);
            acc[j] = __builtin_amdgcn_mfma_f32_16x16x32_bf16(
                pa1, *(const short8*)&Vs[j * 16 + ln][32 + quad * 8], acc[j], 0, 0, 0);
        }
    }

    float invl[4];
#pragma unroll
    for (int r = 0; r < 4; ++r) invl[r] = 1.f / l_r[r];
    ushort* yb = Yb + ((size_t)(b * T_ + qrow)) * D_ + h * HD + ln;
#pragma unroll
    for (int r = 0; r < 4; ++r)
#pragma unroll
        for (int j = 0; j < 8; ++j)
            yb[(size_t)r * D_ + j * 16] = f2b(acc[j][r] * invl[r]);
}

// ---------------------------------------------------------------------------
extern "C" void kernel_launch(void* const* d_in, const int* in_sizes, int n_in,
                              void* d_out, int out_size, void* d_ws, size_t ws_size,
                              hipStream_t stream) {
    const float* x  = (const float*)d_in[0];
    const float* Wq = (const float*)d_in[1];
    const float* Wk = (const float*)d_in[2];
    const float* Wv = (const float*)d_in[3];
    const float* Wo = (const float*)d_in[4];
    float* out = (float*)d_out;

    // Workspace (75.5 MB; round-1 footprint 83.9 MB so ws_size covers it):
    char* w = (char*)d_ws;
    ushort* xb    = (ushort*)w;  w += (size_t)4096 * D_ * 2;      // 16.78 MB
    ushort* WqkvT = (ushort*)w;  w += (size_t)QKV_W * D_ * 2;     // 12.58 MB
    ushort* QKV   = (ushort*)w;  w += (size_t)4096 * QKV_W * 2;   // 25.17 MB
    ushort* Vt    = (ushort*)w;  w += (size_t)B_ * KV_D * T_ * 2; //  4.19 MB
    ushort* Yb    = (ushort*)w;  w += (size_t)4096 * D_ * 2;      // 16.78 MB
    ushort* WoT   = xb;  // alias: xb dead after the fused QKV GEMM

    const int M = B_ * T_;  // 4096
    dim3 blk(256);

    // prep
    cast_f32_bf16<<<(M * D_ / 4 + 255) / 256, blk, 0, stream>>>(x, xb, M * D_ / 4);
    transpose_cast<<<dim3(D_ / 32, D_ / 32), blk, 0, stream>>>(Wq, WqkvT, D_, D_);
    transpose_cast<<<dim3(KV_D / 32, D_ / 32), blk, 0, stream>>>(
        Wk, WqkvT + (size_t)D_ * D_, D_, KV_D);
    transpose_cast<<<dim3(KV_D / 32, D_ / 32), blk, 0, stream>>>(
        Wv, WqkvT + (size_t)(D_ + KV_D) * D_, D_, KV_D);

    // fused QKV projection: bf16 out, 768 WGs (3/CU)
    gemm_bf16_t<true><<<dim3(QKV_W / 128, M / 128), blk, 0, stream>>>(
        xb, WqkvT, QKV, M, QKV_W, D_);

    // Wo transpose reuses xb space (xb dead after fused GEMM, stream-serial)
    transpose_cast<<<dim3(D_ / 32, D_ / 32), blk, 0, stream>>>(Wo, WoT, D_, D_);

    // RoPE in-place on QKV (Q scaled by 1/sqrt(HD))
    const int rope_total = M * (NH + NKV) * 64;
    rope_inplace<<<rope_total / 256, blk, 0, stream>>>(QKV);

    // V columns -> d-major Vt
    transpose_v16<<<dim3(B_ * NKV, T_ / 32, HD / 32), blk, 0, stream>>>(QKV, Vt);

    attn_mfma<<<dim3(B_ * NH, T_ / 64), blk, 0, stream>>>(QKV, Vt, Yb);

    // output projection: bf16 Y x bf16 Wo^T -> fp32 out
    gemm_bf16_t<false><<<dim3(D_ / 128, M / 128), blk, 0, stream>>>(
        Yb, WoT, out, M, D_, D_);
}